// Round 1
// baseline (10935.976 us; speedup 1.0000x reference)
//
#include <hip/hip_runtime.h>
#include <hip/hip_bf16.h>

#define N_NODES 50000
#define N_EDGES 600000
#define HID 128

// ---------------- edge dtype detection ----------------
// If edge_index is int64, the high 32-bit words (odd int32 positions) of the
// first 1024 entries are all zero (values < 50000). If int32, those positions
// are random src values in [0, 50000) -- essentially never all zero.
__global__ void detect_mode(const void* __restrict__ edges, int* __restrict__ flag) {
    __shared__ int any;
    if (threadIdx.x == 0) any = 0;
    __syncthreads();
    const int* p = (const int*)edges;
    if (p[2 * threadIdx.x + 1] != 0) any = 1;  // benign race
    __syncthreads();
    if (threadIdx.x == 0) *flag = (any == 0) ? 1 : 0;  // 1 => int64
}

__device__ __forceinline__ int edge_at(const void* edges, int mode64, long long idx) {
    return mode64 ? (int)((const long long*)edges)[idx] : ((const int*)edges)[idx];
}

// ---------------- CSR build ----------------
__global__ void count_deg(const void* __restrict__ edges, const int* __restrict__ flag,
                          int* __restrict__ deg) {
    int e = blockIdx.x * 256 + threadIdx.x;
    if (e >= N_EDGES) return;
    int m = *flag;
    int d = edge_at(edges, m, (long long)N_EDGES + e);
    if ((unsigned)d < (unsigned)N_NODES) atomicAdd(&deg[d], 1);
}

__global__ void scan_block(const int* __restrict__ deg, int* __restrict__ offs,
                           int* __restrict__ blocksum) {
    __shared__ int sm[256];
    int i = blockIdx.x * 256 + threadIdx.x;
    int v = (i < N_NODES) ? deg[i] : 0;
    sm[threadIdx.x] = v;
    __syncthreads();
    #pragma unroll
    for (int s = 1; s < 256; s <<= 1) {
        int t = (threadIdx.x >= (unsigned)s) ? sm[threadIdx.x - s] : 0;
        __syncthreads();
        sm[threadIdx.x] += t;
        __syncthreads();
    }
    if (i < N_NODES) offs[i] = sm[threadIdx.x] - v;       // exclusive within block
    if (threadIdx.x == 255) blocksum[blockIdx.x] = sm[255];
}

__global__ void scan_top(int* __restrict__ blocksum, int nblocks) {
    __shared__ int sm[256];
    int v = ((int)threadIdx.x < nblocks) ? blocksum[threadIdx.x] : 0;
    sm[threadIdx.x] = v;
    __syncthreads();
    #pragma unroll
    for (int s = 1; s < 256; s <<= 1) {
        int t = (threadIdx.x >= (unsigned)s) ? sm[threadIdx.x - s] : 0;
        __syncthreads();
        sm[threadIdx.x] += t;
        __syncthreads();
    }
    if ((int)threadIdx.x < nblocks) blocksum[threadIdx.x] = sm[threadIdx.x] - v;  // exclusive
    if (threadIdx.x == 255) blocksum[nblocks] = sm[255];  // grand total
}

__global__ void scan_add(int* __restrict__ offs, int* __restrict__ cursor,
                         const int* __restrict__ blocksum, int nblocks) {
    int i = blockIdx.x * 256 + threadIdx.x;
    if (i < N_NODES) {
        int o = offs[i] + blocksum[blockIdx.x];
        offs[i] = o;
        cursor[i] = o;
    }
    if (i == 0) offs[N_NODES] = blocksum[nblocks];
}

__global__ void fill_csr(const void* __restrict__ edges, const int* __restrict__ flag,
                         int* __restrict__ cursor, int* __restrict__ csr) {
    int e = blockIdx.x * 256 + threadIdx.x;
    if (e >= N_EDGES) return;
    int m = *flag;
    int d = edge_at(edges, m, (long long)N_EDGES + e);
    int s = edge_at(edges, m, (long long)e);
    if ((unsigned)d >= (unsigned)N_NODES || (unsigned)s >= (unsigned)N_NODES) return;
    int pos = atomicAdd(&cursor[d], 1);
    csr[pos] = s;
}

// ---------------- mean aggregation (CSR) ----------------
// 32 lanes per node, one float4 (4 features) per lane => 128 features.
__global__ __launch_bounds__(256) void aggregate(const float* __restrict__ h,
                                                 const int* __restrict__ offs,
                                                 const int* __restrict__ csr,
                                                 float* __restrict__ mean) {
    int lane = threadIdx.x & 31;
    int node = blockIdx.x * 8 + (threadIdx.x >> 5);
    if (node >= N_NODES) return;
    int beg = offs[node], end = offs[node + 1];
    float4 acc = make_float4(0.f, 0.f, 0.f, 0.f);
    for (int p = beg; p < end; ++p) {
        int s = csr[p];
        float4 v = ((const float4*)(h + (size_t)s * HID))[lane];
        acc.x += v.x; acc.y += v.y; acc.z += v.z; acc.w += v.w;
    }
    float inv = 1.0f / fmaxf((float)(end - beg), 1.0f);
    float4 r = make_float4(acc.x * inv, acc.y * inv, acc.z * inv, acc.w * inv);
    ((float4*)(mean + (size_t)node * HID))[lane] = r;
}

// ---------------- fused SAGE GEMM ----------------
// out[i,:] = mean[i,:] @ Wl^T + h[i,:] @ Wr^T + b   (optional ReLU)
// Tile: 128 rows x 128 cols, 256 threads, 8x8 per thread, K = 256 in chunks of 32.
template <int RELU>
__global__ __launch_bounds__(256) void sage_gemm(const float* __restrict__ mean,
                                                 const float* __restrict__ h,
                                                 const float* __restrict__ Wl,
                                                 const float* __restrict__ Wr,
                                                 const float* __restrict__ bias,
                                                 float* __restrict__ out) {
    __shared__ float As[32][HID + 4];  // As[k][row]
    __shared__ float Bs[32][HID + 4];  // Bs[k][col] = W[col][k]
    const int tid = threadIdx.x;
    const int rowBase = blockIdx.x * 128;
    const int tx = tid & 15;   // col group: cols tx*8..tx*8+7
    const int ty = tid >> 4;   // row group: rows ty*8..ty*8+7

    float acc[8][8];
    #pragma unroll
    for (int r = 0; r < 8; ++r)
        #pragma unroll
        for (int c = 0; c < 8; ++c) acc[r][c] = 0.f;

    const int cl = tid & 31;   // k-offset within chunk for staging
    const int r0 = tid >> 5;   // 0..7

    #pragma unroll
    for (int kc = 0; kc < 256; kc += 32) {
        const float* A = (kc < 128) ? mean : h;
        const float* W = (kc < 128) ? Wl : Wr;
        const int kOff = kc & 127;
        // Stage A tile: 128 rows x 32 k's  (16 elems/thread, coalesced on k)
        #pragma unroll
        for (int i = 0; i < 16; ++i) {
            int r = r0 * 16 + i;
            int row = rowBase + r;
            As[cl][r] = (row < N_NODES) ? A[(size_t)row * HID + kOff + cl] : 0.f;
        }
        // Stage B tile: Bs[k][j] = W[j*HID + kOff + k]  (coalesced on k)
        #pragma unroll
        for (int i = 0; i < 16; ++i) {
            int j = r0 * 16 + i;
            Bs[cl][j] = W[j * HID + kOff + cl];
        }
        __syncthreads();
        #pragma unroll
        for (int kk = 0; kk < 32; ++kk) {
            float4 a0 = *(const float4*)&As[kk][ty * 8];
            float4 a1 = *(const float4*)&As[kk][ty * 8 + 4];
            float4 b0 = *(const float4*)&Bs[kk][tx * 8];
            float4 b1 = *(const float4*)&Bs[kk][tx * 8 + 4];
            float av[8] = {a0.x, a0.y, a0.z, a0.w, a1.x, a1.y, a1.z, a1.w};
            float bv[8] = {b0.x, b0.y, b0.z, b0.w, b1.x, b1.y, b1.z, b1.w};
            #pragma unroll
            for (int r = 0; r < 8; ++r)
                #pragma unroll
                for (int c = 0; c < 8; ++c)
                    acc[r][c] = fmaf(av[r], bv[c], acc[r][c]);
        }
        __syncthreads();
    }

    const int colBase = tx * 8;
    float4 bb0 = *(const float4*)&bias[colBase];
    float4 bb1 = *(const float4*)&bias[colBase + 4];
    float bv[8] = {bb0.x, bb0.y, bb0.z, bb0.w, bb1.x, bb1.y, bb1.z, bb1.w};
    #pragma unroll
    for (int r = 0; r < 8; ++r) {
        int row = rowBase + ty * 8 + r;
        if (row < N_NODES) {
            float o[8];
            #pragma unroll
            for (int c = 0; c < 8; ++c) {
                o[c] = acc[r][c] + bv[c];
                if (RELU) o[c] = fmaxf(o[c], 0.f);
            }
            float* dp = out + (size_t)row * HID + colBase;
            *(float4*)dp = make_float4(o[0], o[1], o[2], o[3]);
            *(float4*)(dp + 4) = make_float4(o[4], o[5], o[6], o[7]);
        }
    }
}

// ---------------- launch ----------------
extern "C" void kernel_launch(void* const* d_in, const int* in_sizes, int n_in,
                              void* d_out, int out_size, void* d_ws, size_t ws_size,
                              hipStream_t stream) {
    const float* x   = (const float*)d_in[0];
    const void* edges = d_in[1];
    const float* Wl1 = (const float*)d_in[2];
    const float* Wr1 = (const float*)d_in[3];
    const float* b1  = (const float*)d_in[4];
    const float* Wl2 = (const float*)d_in[5];
    const float* Wr2 = (const float*)d_in[6];
    const float* b2  = (const float*)d_in[7];
    const float* Wl3 = (const float*)d_in[8];
    const float* Wr3 = (const float*)d_in[9];
    const float* b3  = (const float*)d_in[10];
    float* out = (float*)d_out;

    char* ws = (char*)d_ws;
    size_t off = 0;
    auto alloc = [&](size_t bytes) -> void* {
        void* p = (void*)(ws + off);
        off += (bytes + 255) & ~(size_t)255;
        return p;
    };
    int* flag     = (int*)alloc(256);
    int* deg      = (int*)alloc((size_t)N_NODES * 4);
    int* offs     = (int*)alloc((size_t)(N_NODES + 1) * 4);
    int* cursor   = (int*)alloc((size_t)N_NODES * 4);
    int* blocksum = (int*)alloc(256 * 4);
    int* csr      = (int*)alloc((size_t)N_EDGES * 4);
    float* mean   = (float*)alloc((size_t)N_NODES * HID * 4);
    float* h1     = (float*)alloc((size_t)N_NODES * HID * 4);
    float* h2     = (float*)alloc((size_t)N_NODES * HID * 4);
    (void)ws_size; (void)in_sizes; (void)n_in; (void)out_size;

    const int EB = (N_EDGES + 255) / 256;       // 2344
    const int NB = (N_NODES + 255) / 256;       // 196
    const int AGG_B = (N_NODES + 7) / 8;        // 6250
    const int GEMM_B = (N_NODES + 127) / 128;   // 391

    hipMemsetAsync(deg, 0, (size_t)N_NODES * 4, stream);
    detect_mode<<<1, 1024, 0, stream>>>(edges, flag);
    count_deg<<<EB, 256, 0, stream>>>(edges, flag, deg);
    scan_block<<<NB, 256, 0, stream>>>(deg, offs, blocksum);
    scan_top<<<1, 256, 0, stream>>>(blocksum, NB);
    scan_add<<<NB, 256, 0, stream>>>(offs, cursor, blocksum, NB);
    fill_csr<<<EB, 256, 0, stream>>>(edges, flag, cursor, csr);

    // Layer 1: relu(sage(x))
    aggregate<<<AGG_B, 256, 0, stream>>>(x, offs, csr, mean);
    sage_gemm<1><<<GEMM_B, 256, 0, stream>>>(mean, x, Wl1, Wr1, b1, h1);
    // Layer 2
    aggregate<<<AGG_B, 256, 0, stream>>>(h1, offs, csr, mean);
    sage_gemm<0><<<GEMM_B, 256, 0, stream>>>(mean, h1, Wl2, Wr2, b2, h2);
    // Layer 3
    aggregate<<<AGG_B, 256, 0, stream>>>(h2, offs, csr, mean);
    sage_gemm<0><<<GEMM_B, 256, 0, stream>>>(mean, h2, Wl3, Wr3, b3, out);
}

// Round 2
// 469.417 us; speedup vs baseline: 23.2969x; 23.2969x over previous
//
#include <hip/hip_runtime.h>
#include <hip/hip_bf16.h>

#define N_NODES 50000
#define N_EDGES 600000
#define HID 128

// ---------------- edge dtype detection ----------------
// If edge_index is int64, the high 32-bit words (odd int32 positions) of the
// first 1024 entries are all zero (values < 50000). If int32, those positions
// are random src values in [0, 50000) -- essentially never all zero.
__global__ void detect_mode(const void* __restrict__ edges, int* __restrict__ flag) {
    __shared__ int any;
    if (threadIdx.x == 0) any = 0;
    __syncthreads();
    const int* p = (const int*)edges;
    if (p[2 * threadIdx.x + 1] != 0) any = 1;  // benign race
    __syncthreads();
    if (threadIdx.x == 0) *flag = (any == 0) ? 1 : 0;  // 1 => int64
}

__device__ __forceinline__ int edge_at(const void* edges, int mode64, long long idx) {
    return mode64 ? (int)((const long long*)edges)[idx] : ((const int*)edges)[idx];
}

// ---------------- CSR build ----------------
__global__ void count_deg(const void* __restrict__ edges, const int* __restrict__ flag,
                          int* __restrict__ deg) {
    int e = blockIdx.x * 256 + threadIdx.x;
    if (e >= N_EDGES) return;
    int m = *flag;
    int d = edge_at(edges, m, (long long)N_EDGES + e);
    if ((unsigned)d < (unsigned)N_NODES) atomicAdd(&deg[d], 1);
}

__global__ void scan_block(const int* __restrict__ deg, int* __restrict__ offs,
                           int* __restrict__ blocksum) {
    __shared__ int sm[256];
    int i = blockIdx.x * 256 + threadIdx.x;
    int v = (i < N_NODES) ? deg[i] : 0;
    sm[threadIdx.x] = v;
    __syncthreads();
    #pragma unroll
    for (int s = 1; s < 256; s <<= 1) {
        int t = (threadIdx.x >= (unsigned)s) ? sm[threadIdx.x - s] : 0;
        __syncthreads();
        sm[threadIdx.x] += t;
        __syncthreads();
    }
    if (i < N_NODES) offs[i] = sm[threadIdx.x] - v;       // exclusive within block
    if (threadIdx.x == 255) blocksum[blockIdx.x] = sm[255];
}

__global__ void scan_top(int* __restrict__ blocksum, int nblocks) {
    __shared__ int sm[256];
    int v = ((int)threadIdx.x < nblocks) ? blocksum[threadIdx.x] : 0;
    sm[threadIdx.x] = v;
    __syncthreads();
    #pragma unroll
    for (int s = 1; s < 256; s <<= 1) {
        int t = (threadIdx.x >= (unsigned)s) ? sm[threadIdx.x - s] : 0;
        __syncthreads();
        sm[threadIdx.x] += t;
        __syncthreads();
    }
    if ((int)threadIdx.x < nblocks) blocksum[threadIdx.x] = sm[threadIdx.x] - v;  // exclusive
    if (threadIdx.x == 255) blocksum[nblocks] = sm[255];  // grand total
}

__global__ void scan_add(int* __restrict__ offs, int* __restrict__ cursor,
                         const int* __restrict__ blocksum, int nblocks) {
    int i = blockIdx.x * 256 + threadIdx.x;
    if (i < N_NODES) {
        int o = offs[i] + blocksum[blockIdx.x];
        offs[i] = o;
        cursor[i] = o;
    }
    if (i == 0) offs[N_NODES] = blocksum[nblocks];
}

__global__ void fill_csr(const void* __restrict__ edges, const int* __restrict__ flag,
                         int* __restrict__ cursor, int* __restrict__ csr) {
    int e = blockIdx.x * 256 + threadIdx.x;
    if (e >= N_EDGES) return;
    int m = *flag;
    int d = edge_at(edges, m, (long long)N_EDGES + e);
    int s = edge_at(edges, m, (long long)e);
    if ((unsigned)d >= (unsigned)N_NODES || (unsigned)s >= (unsigned)N_NODES) return;
    int pos = atomicAdd(&cursor[d], 1);
    csr[pos] = s;
}

// ---------------- mean aggregation (CSR) ----------------
// 32 lanes per node, one float4 (4 features) per lane => 128 features.
__global__ __launch_bounds__(256) void aggregate(const float* __restrict__ h,
                                                 const int* __restrict__ offs,
                                                 const int* __restrict__ csr,
                                                 float* __restrict__ mean) {
    int lane = threadIdx.x & 31;
    int node = blockIdx.x * 8 + (threadIdx.x >> 5);
    if (node >= N_NODES) return;
    int beg = offs[node], end = offs[node + 1];
    float4 acc = make_float4(0.f, 0.f, 0.f, 0.f);
    for (int p = beg; p < end; ++p) {
        int s = csr[p];
        float4 v = ((const float4*)(h + (size_t)s * HID))[lane];
        acc.x += v.x; acc.y += v.y; acc.z += v.z; acc.w += v.w;
    }
    float inv = 1.0f / fmaxf((float)(end - beg), 1.0f);
    float4 r = make_float4(acc.x * inv, acc.y * inv, acc.z * inv, acc.w * inv);
    ((float4*)(mean + (size_t)node * HID))[lane] = r;
}

// ---------------- fused SAGE GEMM ----------------
// out[i,:] = mean[i,:] @ Wl^T + h[i,:] @ Wr^T + b   (optional ReLU)
// Tile: 64 rows x 128 cols, 256 threads, 4x8 per thread (32 acc VGPRs -> no
// spill; previous 8x8 version hit the 256-VGPR cap and thrashed scratch).
// K = 2 phases x 128, staged in BK=16 chunks (runtime loop, NOT unrolled).
template <int RELU>
__global__ __launch_bounds__(256) void sage_gemm(const float* __restrict__ mean,
                                                 const float* __restrict__ h,
                                                 const float* __restrict__ Wl,
                                                 const float* __restrict__ Wr,
                                                 const float* __restrict__ bias,
                                                 float* __restrict__ out) {
    __shared__ float As[16][64 + 4];    // As[k][row]
    __shared__ float Bs[16][128 + 4];   // Bs[k][col] = W[col][k]
    const int tid = threadIdx.x;
    const int rowBase = blockIdx.x * 64;
    const int tx = tid & 15;        // col group: cols tx*8 .. tx*8+7
    const int ty = tid >> 4;        // row group: rows ty*4 .. ty*4+3

    float acc[4][8];
    #pragma unroll
    for (int r = 0; r < 4; ++r)
        #pragma unroll
        for (int c = 0; c < 8; ++c) acc[r][c] = 0.f;

    // A staging: 64 rows x 16 k = 1024 floats, 1 float4/thread.
    const int arow = tid >> 2;          // 0..63
    const int ak   = (tid & 3) * 4;     // 0,4,8,12
    // B staging: 128 cols x 16 k = 2048 floats, 2 float4/thread.
    const int bcol = tid >> 1;          // 0..127
    const int bk   = (tid & 1) * 8;     // 0,8

    const int grow = rowBase + arow;
    const bool rowOk = (grow < N_NODES);

    for (int phase = 0; phase < 2; ++phase) {
        const float* __restrict__ A = phase ? h : mean;
        const float* __restrict__ W = phase ? Wr : Wl;
        const float* aptr = A + (size_t)grow * HID;
        const float* wptr = W + bcol * HID;

        for (int kc = 0; kc < 128; kc += 16) {
            float4 av = rowOk ? *(const float4*)(aptr + kc + ak)
                              : make_float4(0.f, 0.f, 0.f, 0.f);
            float4 bv0 = *(const float4*)(wptr + kc + bk);
            float4 bv1 = *(const float4*)(wptr + kc + bk + 4);
            __syncthreads();   // previous chunk's reads done before overwrite
            As[ak + 0][arow] = av.x;
            As[ak + 1][arow] = av.y;
            As[ak + 2][arow] = av.z;
            As[ak + 3][arow] = av.w;
            Bs[bk + 0][bcol] = bv0.x;
            Bs[bk + 1][bcol] = bv0.y;
            Bs[bk + 2][bcol] = bv0.z;
            Bs[bk + 3][bcol] = bv0.w;
            Bs[bk + 4][bcol] = bv1.x;
            Bs[bk + 5][bcol] = bv1.y;
            Bs[bk + 6][bcol] = bv1.z;
            Bs[bk + 7][bcol] = bv1.w;
            __syncthreads();
            #pragma unroll
            for (int kk = 0; kk < 16; ++kk) {
                float4 a  = *(const float4*)&As[kk][ty * 4];
                float4 b0 = *(const float4*)&Bs[kk][tx * 8];
                float4 b1 = *(const float4*)&Bs[kk][tx * 8 + 4];
                acc[0][0] = fmaf(a.x, b0.x, acc[0][0]);
                acc[0][1] = fmaf(a.x, b0.y, acc[0][1]);
                acc[0][2] = fmaf(a.x, b0.z, acc[0][2]);
                acc[0][3] = fmaf(a.x, b0.w, acc[0][3]);
                acc[0][4] = fmaf(a.x, b1.x, acc[0][4]);
                acc[0][5] = fmaf(a.x, b1.y, acc[0][5]);
                acc[0][6] = fmaf(a.x, b1.z, acc[0][6]);
                acc[0][7] = fmaf(a.x, b1.w, acc[0][7]);
                acc[1][0] = fmaf(a.y, b0.x, acc[1][0]);
                acc[1][1] = fmaf(a.y, b0.y, acc[1][1]);
                acc[1][2] = fmaf(a.y, b0.z, acc[1][2]);
                acc[1][3] = fmaf(a.y, b0.w, acc[1][3]);
                acc[1][4] = fmaf(a.y, b1.x, acc[1][4]);
                acc[1][5] = fmaf(a.y, b1.y, acc[1][5]);
                acc[1][6] = fmaf(a.y, b1.z, acc[1][6]);
                acc[1][7] = fmaf(a.y, b1.w, acc[1][7]);
                acc[2][0] = fmaf(a.z, b0.x, acc[2][0]);
                acc[2][1] = fmaf(a.z, b0.y, acc[2][1]);
                acc[2][2] = fmaf(a.z, b0.z, acc[2][2]);
                acc[2][3] = fmaf(a.z, b0.w, acc[2][3]);
                acc[2][4] = fmaf(a.z, b1.x, acc[2][4]);
                acc[2][5] = fmaf(a.z, b1.y, acc[2][5]);
                acc[2][6] = fmaf(a.z, b1.z, acc[2][6]);
                acc[2][7] = fmaf(a.z, b1.w, acc[2][7]);
                acc[3][0] = fmaf(a.w, b0.x, acc[3][0]);
                acc[3][1] = fmaf(a.w, b0.y, acc[3][1]);
                acc[3][2] = fmaf(a.w, b0.z, acc[3][2]);
                acc[3][3] = fmaf(a.w, b0.w, acc[3][3]);
                acc[3][4] = fmaf(a.w, b1.x, acc[3][4]);
                acc[3][5] = fmaf(a.w, b1.y, acc[3][5]);
                acc[3][6] = fmaf(a.w, b1.z, acc[3][6]);
                acc[3][7] = fmaf(a.w, b1.w, acc[3][7]);
            }
        }
    }

    const int colBase = tx * 8;
    float4 bb0 = *(const float4*)&bias[colBase];
    float4 bb1 = *(const float4*)&bias[colBase + 4];
    #pragma unroll
    for (int r = 0; r < 4; ++r) {
        int row = rowBase + ty * 4 + r;
        if (row < N_NODES) {
            float4 o0 = make_float4(acc[r][0] + bb0.x, acc[r][1] + bb0.y,
                                    acc[r][2] + bb0.z, acc[r][3] + bb0.w);
            float4 o1 = make_float4(acc[r][4] + bb1.x, acc[r][5] + bb1.y,
                                    acc[r][6] + bb1.z, acc[r][7] + bb1.w);
            if (RELU) {
                o0.x = fmaxf(o0.x, 0.f); o0.y = fmaxf(o0.y, 0.f);
                o0.z = fmaxf(o0.z, 0.f); o0.w = fmaxf(o0.w, 0.f);
                o1.x = fmaxf(o1.x, 0.f); o1.y = fmaxf(o1.y, 0.f);
                o1.z = fmaxf(o1.z, 0.f); o1.w = fmaxf(o1.w, 0.f);
            }
            float* dp = out + (size_t)row * HID + colBase;
            *(float4*)dp = o0;
            *(float4*)(dp + 4) = o1;
        }
    }
}

// ---------------- launch ----------------
extern "C" void kernel_launch(void* const* d_in, const int* in_sizes, int n_in,
                              void* d_out, int out_size, void* d_ws, size_t ws_size,
                              hipStream_t stream) {
    const float* x   = (const float*)d_in[0];
    const void* edges = d_in[1];
    const float* Wl1 = (const float*)d_in[2];
    const float* Wr1 = (const float*)d_in[3];
    const float* b1  = (const float*)d_in[4];
    const float* Wl2 = (const float*)d_in[5];
    const float* Wr2 = (const float*)d_in[6];
    const float* b2  = (const float*)d_in[7];
    const float* Wl3 = (const float*)d_in[8];
    const float* Wr3 = (const float*)d_in[9];
    const float* b3  = (const float*)d_in[10];
    float* out = (float*)d_out;

    char* ws = (char*)d_ws;
    size_t off = 0;
    auto alloc = [&](size_t bytes) -> void* {
        void* p = (void*)(ws + off);
        off += (bytes + 255) & ~(size_t)255;
        return p;
    };
    int* flag     = (int*)alloc(256);
    int* deg      = (int*)alloc((size_t)N_NODES * 4);
    int* offs     = (int*)alloc((size_t)(N_NODES + 1) * 4);
    int* cursor   = (int*)alloc((size_t)N_NODES * 4);
    int* blocksum = (int*)alloc(256 * 4);
    int* csr      = (int*)alloc((size_t)N_EDGES * 4);
    float* mean   = (float*)alloc((size_t)N_NODES * HID * 4);
    float* h1     = (float*)alloc((size_t)N_NODES * HID * 4);
    float* h2     = (float*)alloc((size_t)N_NODES * HID * 4);
    (void)ws_size; (void)in_sizes; (void)n_in; (void)out_size;

    const int EB = (N_EDGES + 255) / 256;       // 2344
    const int NB = (N_NODES + 255) / 256;       // 196
    const int AGG_B = (N_NODES + 7) / 8;        // 6250
    const int GEMM_B = (N_NODES + 63) / 64;     // 782

    hipMemsetAsync(deg, 0, (size_t)N_NODES * 4, stream);
    detect_mode<<<1, 1024, 0, stream>>>(edges, flag);
    count_deg<<<EB, 256, 0, stream>>>(edges, flag, deg);
    scan_block<<<NB, 256, 0, stream>>>(deg, offs, blocksum);
    scan_top<<<1, 256, 0, stream>>>(blocksum, NB);
    scan_add<<<NB, 256, 0, stream>>>(offs, cursor, blocksum, NB);
    fill_csr<<<EB, 256, 0, stream>>>(edges, flag, cursor, csr);

    // Layer 1: relu(sage(x))
    aggregate<<<AGG_B, 256, 0, stream>>>(x, offs, csr, mean);
    sage_gemm<1><<<GEMM_B, 256, 0, stream>>>(mean, x, Wl1, Wr1, b1, h1);
    // Layer 2
    aggregate<<<AGG_B, 256, 0, stream>>>(h1, offs, csr, mean);
    sage_gemm<0><<<GEMM_B, 256, 0, stream>>>(mean, h1, Wl2, Wr2, b2, h2);
    // Layer 3
    aggregate<<<AGG_B, 256, 0, stream>>>(h2, offs, csr, mean);
    sage_gemm<0><<<GEMM_B, 256, 0, stream>>>(mean, h2, Wl3, Wr3, b3, out);
}

// Round 3
// 459.398 us; speedup vs baseline: 23.8050x; 1.0218x over previous
//
#include <hip/hip_runtime.h>
#include <hip/hip_bf16.h>

#define N_NODES 50000
#define N_EDGES 600000
#define HID 128

// ---------------- edge dtype detection ----------------
__global__ void detect_mode(const void* __restrict__ edges, int* __restrict__ flag) {
    __shared__ int any;
    if (threadIdx.x == 0) any = 0;
    __syncthreads();
    const int* p = (const int*)edges;
    if (p[2 * threadIdx.x + 1] != 0) any = 1;  // benign race
    __syncthreads();
    if (threadIdx.x == 0) *flag = (any == 0) ? 1 : 0;  // 1 => int64
}

__device__ __forceinline__ int edge_at(const void* edges, int mode64, long long idx) {
    return mode64 ? (int)((const long long*)edges)[idx] : ((const int*)edges)[idx];
}

// ---------------- CSR build ----------------
__global__ void count_deg(const void* __restrict__ edges, const int* __restrict__ flag,
                          int* __restrict__ deg) {
    int e = blockIdx.x * 256 + threadIdx.x;
    if (e >= N_EDGES) return;
    int m = *flag;
    int d = edge_at(edges, m, (long long)N_EDGES + e);
    if ((unsigned)d < (unsigned)N_NODES) atomicAdd(&deg[d], 1);
}

__global__ void scan_block(const int* __restrict__ deg, int* __restrict__ offs,
                           int* __restrict__ blocksum) {
    __shared__ int sm[256];
    int i = blockIdx.x * 256 + threadIdx.x;
    int v = (i < N_NODES) ? deg[i] : 0;
    sm[threadIdx.x] = v;
    __syncthreads();
    #pragma unroll
    for (int s = 1; s < 256; s <<= 1) {
        int t = (threadIdx.x >= (unsigned)s) ? sm[threadIdx.x - s] : 0;
        __syncthreads();
        sm[threadIdx.x] += t;
        __syncthreads();
    }
    if (i < N_NODES) offs[i] = sm[threadIdx.x] - v;
    if (threadIdx.x == 255) blocksum[blockIdx.x] = sm[255];
}

__global__ void scan_top(int* __restrict__ blocksum, int nblocks) {
    __shared__ int sm[256];
    int v = ((int)threadIdx.x < nblocks) ? blocksum[threadIdx.x] : 0;
    sm[threadIdx.x] = v;
    __syncthreads();
    #pragma unroll
    for (int s = 1; s < 256; s <<= 1) {
        int t = (threadIdx.x >= (unsigned)s) ? sm[threadIdx.x - s] : 0;
        __syncthreads();
        sm[threadIdx.x] += t;
        __syncthreads();
    }
    if ((int)threadIdx.x < nblocks) blocksum[threadIdx.x] = sm[threadIdx.x] - v;
    if (threadIdx.x == 255) blocksum[nblocks] = sm[255];
}

__global__ void scan_add(int* __restrict__ offs, int* __restrict__ cursor,
                         const int* __restrict__ blocksum, int nblocks) {
    int i = blockIdx.x * 256 + threadIdx.x;
    if (i < N_NODES) {
        int o = offs[i] + blocksum[blockIdx.x];
        offs[i] = o;
        cursor[i] = o;
    }
    if (i == 0) offs[N_NODES] = blocksum[nblocks];
}

__global__ void fill_csr(const void* __restrict__ edges, const int* __restrict__ flag,
                         int* __restrict__ cursor, int* __restrict__ csr) {
    int e = blockIdx.x * 256 + threadIdx.x;
    if (e >= N_EDGES) return;
    int m = *flag;
    int d = edge_at(edges, m, (long long)N_EDGES + e);
    int s = edge_at(edges, m, (long long)e);
    if ((unsigned)d >= (unsigned)N_NODES || (unsigned)s >= (unsigned)N_NODES) return;
    int pos = atomicAdd(&cursor[d], 1);
    csr[pos] = s;
}

// ---------------- mean aggregation (CSR) ----------------
// 32 lanes per node, one float4 per lane = 128 features.
// 4-way unrolled gather: 4 independent csr-index loads + 4 independent row
// gathers per iteration -> 4x memory-level parallelism on the dependent chain.
__global__ __launch_bounds__(256) void aggregate(const float* __restrict__ h,
                                                 const int* __restrict__ offs,
                                                 const int* __restrict__ csr,
                                                 float* __restrict__ mean) {
    int lane = threadIdx.x & 31;
    int node = blockIdx.x * 8 + (threadIdx.x >> 5);
    if (node >= N_NODES) return;
    int beg = offs[node], end = offs[node + 1];
    float4 acc = make_float4(0.f, 0.f, 0.f, 0.f);
    int p = beg;
    for (; p + 4 <= end; p += 4) {
        int s0 = csr[p], s1 = csr[p + 1], s2 = csr[p + 2], s3 = csr[p + 3];
        float4 v0 = ((const float4*)(h + (size_t)s0 * HID))[lane];
        float4 v1 = ((const float4*)(h + (size_t)s1 * HID))[lane];
        float4 v2 = ((const float4*)(h + (size_t)s2 * HID))[lane];
        float4 v3 = ((const float4*)(h + (size_t)s3 * HID))[lane];
        acc.x += (v0.x + v1.x) + (v2.x + v3.x);
        acc.y += (v0.y + v1.y) + (v2.y + v3.y);
        acc.z += (v0.z + v1.z) + (v2.z + v3.z);
        acc.w += (v0.w + v1.w) + (v2.w + v3.w);
    }
    for (; p < end; ++p) {
        int s = csr[p];
        float4 v = ((const float4*)(h + (size_t)s * HID))[lane];
        acc.x += v.x; acc.y += v.y; acc.z += v.z; acc.w += v.w;
    }
    float inv = 1.0f / fmaxf((float)(end - beg), 1.0f);
    ((float4*)(mean + (size_t)node * HID))[lane] =
        make_float4(acc.x * inv, acc.y * inv, acc.z * inv, acc.w * inv);
}

// ---------------- fused SAGE GEMM ----------------
// out[i,:] = mean[i,:] @ Wl^T + h[i,:] @ Wr^T + b   (optional ReLU)
// 128x128 tile, 256 threads, 8x8 per thread (split 4+4 with 64-offset halves
// so LDS reads are 2-way bank aliased = free). 0.5 B LDS per FLOP = CU balance.
// Register-double-buffered staging (load chunk k+1 during compute of k).
template <int RELU>
__global__ __launch_bounds__(256, 2) void sage_gemm(const float* __restrict__ mean,
                                                    const float* __restrict__ h,
                                                    const float* __restrict__ Wl,
                                                    const float* __restrict__ Wr,
                                                    const float* __restrict__ bias,
                                                    float* __restrict__ out) {
    __shared__ float As[16][132];   // As[k][row], stride 132 (mod32=4)
    __shared__ float Bs[16][132];   // Bs[k][col] = W[col][k]
    const int tid = threadIdx.x;
    const int rowBase = blockIdx.x * 128;
    const int tx = tid & 15;        // cols tx*4..+3 and 64+tx*4..+3
    const int ty = tid >> 4;        // rows ty*4..+3 and 64+ty*4..+3

    float acc[2][2][4][4];          // [rowHalf][colHalf][r][c]
    #pragma unroll
    for (int a = 0; a < 2; ++a)
        #pragma unroll
        for (int b = 0; b < 2; ++b)
            #pragma unroll
            for (int r = 0; r < 4; ++r)
                #pragma unroll
                for (int c = 0; c < 4; ++c) acc[a][b][r][c] = 0.f;

    // Staging: each thread loads 8 A floats + 8 B floats per chunk.
    const int srow = tid >> 1;          // 0..127
    const int sk   = (tid & 1) * 8;     // 0 or 8
    const int growA = rowBase + srow;
    const bool rowOk = (growA < N_NODES);

    const float* Aph[2] = {mean, h};
    const float* Wph[2] = {Wl, Wr};
    const float4 fz = make_float4(0.f, 0.f, 0.f, 0.f);

    float4 ga0, ga1, gb0, gb1;
    {
        const float* ap = Aph[0] + (size_t)growA * HID + sk;
        ga0 = rowOk ? *(const float4*)ap : fz;
        ga1 = rowOk ? *(const float4*)(ap + 4) : fz;
        const float* wp = Wph[0] + srow * HID + sk;
        gb0 = *(const float4*)wp;
        gb1 = *(const float4*)(wp + 4);
    }

    for (int iter = 0; iter < 16; ++iter) {
        __syncthreads();   // previous chunk's LDS reads complete
        As[sk + 0][srow] = ga0.x; As[sk + 1][srow] = ga0.y;
        As[sk + 2][srow] = ga0.z; As[sk + 3][srow] = ga0.w;
        As[sk + 4][srow] = ga1.x; As[sk + 5][srow] = ga1.y;
        As[sk + 6][srow] = ga1.z; As[sk + 7][srow] = ga1.w;
        Bs[sk + 0][srow] = gb0.x; Bs[sk + 1][srow] = gb0.y;
        Bs[sk + 2][srow] = gb0.z; Bs[sk + 3][srow] = gb0.w;
        Bs[sk + 4][srow] = gb1.x; Bs[sk + 5][srow] = gb1.y;
        Bs[sk + 6][srow] = gb1.z; Bs[sk + 7][srow] = gb1.w;
        __syncthreads();
        if (iter < 15) {   // prefetch next chunk into registers during compute
            int ni = iter + 1;
            int ph = ni >> 3;
            int kc = (ni & 7) * 16;
            const float* ap = Aph[ph] + (size_t)growA * HID + kc + sk;
            ga0 = rowOk ? *(const float4*)ap : fz;
            ga1 = rowOk ? *(const float4*)(ap + 4) : fz;
            const float* wp = Wph[ph] + srow * HID + kc + sk;
            gb0 = *(const float4*)wp;
            gb1 = *(const float4*)(wp + 4);
        }
        #pragma unroll
        for (int kk = 0; kk < 16; ++kk) {
            float4 a0 = *(const float4*)&As[kk][ty * 4];
            float4 a1 = *(const float4*)&As[kk][64 + ty * 4];
            float4 b0 = *(const float4*)&Bs[kk][tx * 4];
            float4 b1 = *(const float4*)&Bs[kk][64 + tx * 4];
            float ar[2][4] = {{a0.x, a0.y, a0.z, a0.w}, {a1.x, a1.y, a1.z, a1.w}};
            float br[2][4] = {{b0.x, b0.y, b0.z, b0.w}, {b1.x, b1.y, b1.z, b1.w}};
            #pragma unroll
            for (int rh = 0; rh < 2; ++rh)
                #pragma unroll
                for (int r = 0; r < 4; ++r)
                    #pragma unroll
                    for (int ch = 0; ch < 2; ++ch)
                        #pragma unroll
                        for (int c = 0; c < 4; ++c)
                            acc[rh][ch][r][c] = fmaf(ar[rh][r], br[ch][c], acc[rh][ch][r][c]);
        }
    }

    float4 bb[2];
    bb[0] = *(const float4*)&bias[tx * 4];
    bb[1] = *(const float4*)&bias[64 + tx * 4];
    #pragma unroll
    for (int rh = 0; rh < 2; ++rh)
        #pragma unroll
        for (int r = 0; r < 4; ++r) {
            int row = rowBase + rh * 64 + ty * 4 + r;
            if (row < N_NODES) {
                #pragma unroll
                for (int ch = 0; ch < 2; ++ch) {
                    float4 o = make_float4(acc[rh][ch][r][0] + bb[ch].x,
                                           acc[rh][ch][r][1] + bb[ch].y,
                                           acc[rh][ch][r][2] + bb[ch].z,
                                           acc[rh][ch][r][3] + bb[ch].w);
                    if (RELU) {
                        o.x = fmaxf(o.x, 0.f); o.y = fmaxf(o.y, 0.f);
                        o.z = fmaxf(o.z, 0.f); o.w = fmaxf(o.w, 0.f);
                    }
                    *(float4*)(out + (size_t)row * HID + ch * 64 + tx * 4) = o;
                }
            }
        }
}

// ---------------- launch ----------------
extern "C" void kernel_launch(void* const* d_in, const int* in_sizes, int n_in,
                              void* d_out, int out_size, void* d_ws, size_t ws_size,
                              hipStream_t stream) {
    const float* x   = (const float*)d_in[0];
    const void* edges = d_in[1];
    const float* Wl1 = (const float*)d_in[2];
    const float* Wr1 = (const float*)d_in[3];
    const float* b1  = (const float*)d_in[4];
    const float* Wl2 = (const float*)d_in[5];
    const float* Wr2 = (const float*)d_in[6];
    const float* b2  = (const float*)d_in[7];
    const float* Wl3 = (const float*)d_in[8];
    const float* Wr3 = (const float*)d_in[9];
    const float* b3  = (const float*)d_in[10];
    float* out = (float*)d_out;

    char* ws = (char*)d_ws;
    size_t off = 0;
    auto alloc = [&](size_t bytes) -> void* {
        void* p = (void*)(ws + off);
        off += (bytes + 255) & ~(size_t)255;
        return p;
    };
    int* flag     = (int*)alloc(256);
    int* deg      = (int*)alloc((size_t)N_NODES * 4);
    int* offs     = (int*)alloc((size_t)(N_NODES + 1) * 4);
    int* cursor   = (int*)alloc((size_t)N_NODES * 4);
    int* blocksum = (int*)alloc(256 * 4);
    int* csr      = (int*)alloc((size_t)N_EDGES * 4);
    float* mean   = (float*)alloc((size_t)N_NODES * HID * 4);
    float* h1     = (float*)alloc((size_t)N_NODES * HID * 4);
    float* h2     = (float*)alloc((size_t)N_NODES * HID * 4);
    (void)ws_size; (void)in_sizes; (void)n_in; (void)out_size;

    const int EB = (N_EDGES + 255) / 256;       // 2344
    const int NB = (N_NODES + 255) / 256;       // 196
    const int AGG_B = (N_NODES + 7) / 8;        // 6250
    const int GEMM_B = (N_NODES + 127) / 128;   // 391

    hipMemsetAsync(deg, 0, (size_t)N_NODES * 4, stream);
    detect_mode<<<1, 1024, 0, stream>>>(edges, flag);
    count_deg<<<EB, 256, 0, stream>>>(edges, flag, deg);
    scan_block<<<NB, 256, 0, stream>>>(deg, offs, blocksum);
    scan_top<<<1, 256, 0, stream>>>(blocksum, NB);
    scan_add<<<NB, 256, 0, stream>>>(offs, cursor, blocksum, NB);
    fill_csr<<<EB, 256, 0, stream>>>(edges, flag, cursor, csr);

    // Layer 1: relu(sage(x))
    aggregate<<<AGG_B, 256, 0, stream>>>(x, offs, csr, mean);
    sage_gemm<1><<<GEMM_B, 256, 0, stream>>>(mean, x, Wl1, Wr1, b1, h1);
    // Layer 2
    aggregate<<<AGG_B, 256, 0, stream>>>(h1, offs, csr, mean);
    sage_gemm<0><<<GEMM_B, 256, 0, stream>>>(mean, h1, Wl2, Wr2, b2, h2);
    // Layer 3
    aggregate<<<AGG_B, 256, 0, stream>>>(h2, offs, csr, mean);
    sage_gemm<0><<<GEMM_B, 256, 0, stream>>>(mean, h2, Wl3, Wr3, b3, out);
}

// Round 4
// 355.978 us; speedup vs baseline: 30.7209x; 1.2905x over previous
//
#include <hip/hip_runtime.h>
#include <hip/hip_bf16.h>

#define N_NODES 50000
#define N_EDGES 600000
#define HID 128

typedef __attribute__((ext_vector_type(8))) short s8v;   // 8 bf16 = 4 VGPR
typedef __attribute__((ext_vector_type(4))) float f4v;   // MFMA acc

// ---------------- bf16 helpers ----------------
__device__ __forceinline__ unsigned short f2bf(float x) {
    unsigned u = __float_as_uint(x);
    unsigned r = u + 0x7FFFu + ((u >> 16) & 1u);   // RNE
    return (unsigned short)(r >> 16);
}
__device__ __forceinline__ float bf2f(unsigned short u) {
    return __uint_as_float((unsigned)u << 16);
}
__device__ __forceinline__ void split_bf(float x, unsigned short& hi, unsigned short& lo) {
    hi = f2bf(x);
    lo = f2bf(x - bf2f(hi));
}

// ---------------- edge dtype detection ----------------
__global__ void detect_mode(const void* __restrict__ edges, int* __restrict__ flag) {
    __shared__ int any;
    if (threadIdx.x == 0) any = 0;
    __syncthreads();
    const int* p = (const int*)edges;
    if (p[2 * threadIdx.x + 1] != 0) any = 1;  // benign race
    __syncthreads();
    if (threadIdx.x == 0) *flag = (any == 0) ? 1 : 0;  // 1 => int64
}

__device__ __forceinline__ int edge_at(const void* edges, int mode64, long long idx) {
    return mode64 ? (int)((const long long*)edges)[idx] : ((const int*)edges)[idx];
}

// ---------------- CSR build ----------------
__global__ void count_deg(const void* __restrict__ edges, const int* __restrict__ flag,
                          int* __restrict__ deg) {
    int e = blockIdx.x * 256 + threadIdx.x;
    if (e >= N_EDGES) return;
    int m = *flag;
    int d = edge_at(edges, m, (long long)N_EDGES + e);
    if ((unsigned)d < (unsigned)N_NODES) atomicAdd(&deg[d], 1);
}

__global__ void scan_block(const int* __restrict__ deg, int* __restrict__ offs,
                           int* __restrict__ blocksum) {
    __shared__ int sm[256];
    int i = blockIdx.x * 256 + threadIdx.x;
    int v = (i < N_NODES) ? deg[i] : 0;
    sm[threadIdx.x] = v;
    __syncthreads();
    #pragma unroll
    for (int s = 1; s < 256; s <<= 1) {
        int t = (threadIdx.x >= (unsigned)s) ? sm[threadIdx.x - s] : 0;
        __syncthreads();
        sm[threadIdx.x] += t;
        __syncthreads();
    }
    if (i < N_NODES) offs[i] = sm[threadIdx.x] - v;
    if (threadIdx.x == 255) blocksum[blockIdx.x] = sm[255];
}

__global__ void scan_top(int* __restrict__ blocksum, int nblocks) {
    __shared__ int sm[256];
    int v = ((int)threadIdx.x < nblocks) ? blocksum[threadIdx.x] : 0;
    sm[threadIdx.x] = v;
    __syncthreads();
    #pragma unroll
    for (int s = 1; s < 256; s <<= 1) {
        int t = (threadIdx.x >= (unsigned)s) ? sm[threadIdx.x - s] : 0;
        __syncthreads();
        sm[threadIdx.x] += t;
        __syncthreads();
    }
    if ((int)threadIdx.x < nblocks) blocksum[threadIdx.x] = sm[threadIdx.x] - v;
    if (threadIdx.x == 255) blocksum[nblocks] = sm[255];
}

__global__ void scan_add(int* __restrict__ offs, int* __restrict__ cursor,
                         const int* __restrict__ blocksum, int nblocks) {
    int i = blockIdx.x * 256 + threadIdx.x;
    if (i < N_NODES) {
        int o = offs[i] + blocksum[blockIdx.x];
        offs[i] = o;
        cursor[i] = o;
    }
    if (i == 0) offs[N_NODES] = blocksum[nblocks];
}

__global__ void fill_csr(const void* __restrict__ edges, const int* __restrict__ flag,
                         int* __restrict__ cursor, int* __restrict__ csr) {
    int e = blockIdx.x * 256 + threadIdx.x;
    if (e >= N_EDGES) return;
    int m = *flag;
    int d = edge_at(edges, m, (long long)N_EDGES + e);
    int s = edge_at(edges, m, (long long)e);
    if ((unsigned)d >= (unsigned)N_NODES || (unsigned)s >= (unsigned)N_NODES) return;
    int pos = atomicAdd(&cursor[d], 1);
    csr[pos] = s;
}

// ---------------- precision-split conversions ----------------
// 6 weight matrices (Wl1,Wr1,Wl2,Wr2,Wl3,Wr3) -> hi/lo bf16 planes.
__global__ void convert_w(const float* __restrict__ m0, const float* __restrict__ m1,
                          const float* __restrict__ m2, const float* __restrict__ m3,
                          const float* __restrict__ m4, const float* __restrict__ m5,
                          unsigned short* __restrict__ whi, unsigned short* __restrict__ wlo) {
    int idx = blockIdx.x * 256 + threadIdx.x;
    if (idx >= 6 * HID * HID) return;
    int mat = idx >> 14, off = idx & 16383;
    const float* src = mat == 0 ? m0 : mat == 1 ? m1 : mat == 2 ? m2
                     : mat == 3 ? m3 : mat == 4 ? m4 : m5;
    unsigned short h, l;
    split_bf(src[off], h, l);
    whi[idx] = h; wlo[idx] = l;
}

__global__ void split_f32(const float* __restrict__ x, unsigned short* __restrict__ hi,
                          unsigned short* __restrict__ lo, int n4) {
    int i = blockIdx.x * 256 + threadIdx.x;
    if (i >= n4) return;
    float4 v = ((const float4*)x)[i];
    ushort4 h, l;
    split_bf(v.x, h.x, l.x);
    split_bf(v.y, h.y, l.y);
    split_bf(v.z, h.z, l.z);
    split_bf(v.w, h.w, l.w);
    ((ushort4*)hi)[i] = h;
    ((ushort4*)lo)[i] = l;
}

// ---------------- mean aggregation (bf16-hi gather, hi/lo split output) ------
// 32 lanes per node, ushort4 (4 feats) per lane. 4-way unrolled gather for MLP.
// Gathers only the hi plane: halves gather traffic; injected error ~2^-9/sqrt(deg).
__global__ __launch_bounds__(256) void aggregate_bf16(const unsigned short* __restrict__ h,
                                                      const int* __restrict__ offs,
                                                      const int* __restrict__ csr,
                                                      unsigned short* __restrict__ mhi,
                                                      unsigned short* __restrict__ mlo) {
    int lane = threadIdx.x & 31;
    int node = blockIdx.x * 8 + (threadIdx.x >> 5);
    if (node >= N_NODES) return;
    int beg = offs[node], end = offs[node + 1];
    float a0 = 0.f, a1 = 0.f, a2 = 0.f, a3 = 0.f;
    int p = beg;
    for (; p + 4 <= end; p += 4) {
        int s0 = csr[p], s1 = csr[p + 1], s2 = csr[p + 2], s3 = csr[p + 3];
        ushort4 v0 = ((const ushort4*)(h + (size_t)s0 * HID))[lane];
        ushort4 v1 = ((const ushort4*)(h + (size_t)s1 * HID))[lane];
        ushort4 v2 = ((const ushort4*)(h + (size_t)s2 * HID))[lane];
        ushort4 v3 = ((const ushort4*)(h + (size_t)s3 * HID))[lane];
        a0 += (bf2f(v0.x) + bf2f(v1.x)) + (bf2f(v2.x) + bf2f(v3.x));
        a1 += (bf2f(v0.y) + bf2f(v1.y)) + (bf2f(v2.y) + bf2f(v3.y));
        a2 += (bf2f(v0.z) + bf2f(v1.z)) + (bf2f(v2.z) + bf2f(v3.z));
        a3 += (bf2f(v0.w) + bf2f(v1.w)) + (bf2f(v2.w) + bf2f(v3.w));
    }
    for (; p < end; ++p) {
        int s = csr[p];
        ushort4 v = ((const ushort4*)(h + (size_t)s * HID))[lane];
        a0 += bf2f(v.x); a1 += bf2f(v.y); a2 += bf2f(v.z); a3 += bf2f(v.w);
    }
    float inv = 1.0f / fmaxf((float)(end - beg), 1.0f);
    a0 *= inv; a1 *= inv; a2 *= inv; a3 *= inv;
    ushort4 hh, ll;
    split_bf(a0, hh.x, ll.x);
    split_bf(a1, hh.y, ll.y);
    split_bf(a2, hh.z, ll.z);
    split_bf(a3, hh.w, ll.w);
    ((ushort4*)(mhi + (size_t)node * HID))[lane] = hh;
    ((ushort4*)(mlo + (size_t)node * HID))[lane] = ll;
}

// ---------------- MFMA SAGE GEMM (split-bf16, fp32-accurate) ----------------
// out[i,:] = mean[i,:] @ Wl^T + h[i,:] @ Wr^T + b  via 16x16x32 bf16 MFMA.
// 3-term split per product: hi*whi + lo*whi + hi*wlo (err ~2^-18).
// Block 256 thr = 4 waves; tile 128x128; wave -> 64x64 quadrant (4x4 MFMA tiles).
// No LDS in main loop: frags loaded register-direct (W is L2-hot, A is L3-hot),
// explicit 2-deep double buffering. K = 2 phases x 128, chunked 32.
// Frag layouts (HW-verified m89/m91): A[m=lane&15][k=(lane>>4)*8+j],
// B[n=lane&15][k=...] from row-major W[n][k]; D: col=lane&15, row=(lane>>4)*4+reg.
template <int RELU, int FINAL>
__global__ __launch_bounds__(256, 2) void sage_mfma(
    const unsigned short* __restrict__ Mhi, const unsigned short* __restrict__ Mlo,
    const unsigned short* __restrict__ Hhi, const unsigned short* __restrict__ Hlo,
    const unsigned short* __restrict__ Whi, const unsigned short* __restrict__ Wlo,
    const float* __restrict__ bias,
    unsigned short* __restrict__ ohi, unsigned short* __restrict__ olo,
    float* __restrict__ of32) {
    const int tid = threadIdx.x;
    const int wave = tid >> 6, lane = tid & 63;
    const int mIdx = lane & 15, q = lane >> 4;
    const int wrow = (wave & 1) * 64, wcol = (wave >> 1) * 64;
    const int rowBase = blockIdx.x * 128;

    size_t aoff[4], boff[4];
    #pragma unroll
    for (int t = 0; t < 4; ++t) {
        int node = rowBase + wrow + t * 16 + mIdx;
        if (node > N_NODES - 1) node = N_NODES - 1;   // clamp; store is guarded
        aoff[t] = (size_t)node * HID + q * 8;
        boff[t] = (size_t)(wcol + t * 16 + mIdx) * HID + q * 8;
    }

    f4v acc[4][4];
    #pragma unroll
    for (int a = 0; a < 4; ++a)
        #pragma unroll
        for (int b = 0; b < 4; ++b) acc[a][b] = (f4v){0.f, 0.f, 0.f, 0.f};

    s8v Ah[2][4], Al[2][4], Bh[2][4], Bl[2][4];

    auto load = [&](int i, int buf) {
        const unsigned short* ah_ = (i < 4) ? Mhi : Hhi;
        const unsigned short* al_ = (i < 4) ? Mlo : Hlo;
        const int kc = (i & 3) * 32;
        const int wb = (i < 4) ? 0 : HID * HID;   // Wl then Wr
        #pragma unroll
        for (int t = 0; t < 4; ++t) {
            Ah[buf][t] = *(const s8v*)(ah_ + aoff[t] + kc);
            Al[buf][t] = *(const s8v*)(al_ + aoff[t] + kc);
            Bh[buf][t] = *(const s8v*)(Whi + wb + boff[t] + kc);
            Bl[buf][t] = *(const s8v*)(Wlo + wb + boff[t] + kc);
        }
    };
    auto compute = [&](int buf) {
        #pragma unroll
        for (int mt = 0; mt < 4; ++mt)
            #pragma unroll
            for (int nt = 0; nt < 4; ++nt) {
                acc[mt][nt] = __builtin_amdgcn_mfma_f32_16x16x32_bf16(
                    Ah[buf][mt], Bh[buf][nt], acc[mt][nt], 0, 0, 0);
                acc[mt][nt] = __builtin_amdgcn_mfma_f32_16x16x32_bf16(
                    Al[buf][mt], Bh[buf][nt], acc[mt][nt], 0, 0, 0);
                acc[mt][nt] = __builtin_amdgcn_mfma_f32_16x16x32_bf16(
                    Ah[buf][mt], Bl[buf][nt], acc[mt][nt], 0, 0, 0);
            }
    };

    load(0, 0);
    #pragma unroll
    for (int i = 0; i < 8; ++i) {
        if (i < 7) load(i + 1, (i + 1) & 1);
        compute(i & 1);
    }

    float bv[4];
    #pragma unroll
    for (int nt = 0; nt < 4; ++nt) bv[nt] = bias[wcol + nt * 16 + mIdx];

    #pragma unroll
    for (int mt = 0; mt < 4; ++mt)
        #pragma unroll
        for (int r = 0; r < 4; ++r) {
            int node = rowBase + wrow + mt * 16 + q * 4 + r;
            if (node < N_NODES) {
                #pragma unroll
                for (int nt = 0; nt < 4; ++nt) {
                    int feat = wcol + nt * 16 + mIdx;
                    float v = acc[mt][nt][r] + bv[nt];
                    if (RELU) v = fmaxf(v, 0.f);
                    size_t oidx = (size_t)node * HID + feat;
                    if (FINAL) {
                        of32[oidx] = v;
                    } else {
                        unsigned short hh, ll;
                        split_bf(v, hh, ll);
                        ohi[oidx] = hh;
                        olo[oidx] = ll;
                    }
                }
            }
        }
}

// ---------------- launch ----------------
extern "C" void kernel_launch(void* const* d_in, const int* in_sizes, int n_in,
                              void* d_out, int out_size, void* d_ws, size_t ws_size,
                              hipStream_t stream) {
    const float* x   = (const float*)d_in[0];
    const void* edges = d_in[1];
    const float* Wl1 = (const float*)d_in[2];
    const float* Wr1 = (const float*)d_in[3];
    const float* b1  = (const float*)d_in[4];
    const float* Wl2 = (const float*)d_in[5];
    const float* Wr2 = (const float*)d_in[6];
    const float* b2  = (const float*)d_in[7];
    const float* Wl3 = (const float*)d_in[8];
    const float* Wr3 = (const float*)d_in[9];
    const float* b3  = (const float*)d_in[10];
    float* out = (float*)d_out;

    char* ws = (char*)d_ws;
    size_t off = 0;
    auto alloc = [&](size_t bytes) -> void* {
        void* p = (void*)(ws + off);
        off += (bytes + 255) & ~(size_t)255;
        return p;
    };
    typedef unsigned short u16;
    const size_t FEAT = (size_t)N_NODES * HID;
    int* flag     = (int*)alloc(256);
    int* deg      = (int*)alloc((size_t)N_NODES * 4);
    int* offs     = (int*)alloc((size_t)(N_NODES + 1) * 4);
    int* cursor   = (int*)alloc((size_t)N_NODES * 4);
    int* blocksum = (int*)alloc(256 * 4);
    int* csr      = (int*)alloc((size_t)N_EDGES * 4);
    u16* whi      = (u16*)alloc((size_t)6 * HID * HID * 2);
    u16* wlo      = (u16*)alloc((size_t)6 * HID * HID * 2);
    u16* xhi      = (u16*)alloc(FEAT * 2);   // also reused as h2_hi
    u16* xlo      = (u16*)alloc(FEAT * 2);   // also reused as h2_lo
    u16* h1hi     = (u16*)alloc(FEAT * 2);
    u16* h1lo     = (u16*)alloc(FEAT * 2);
    u16* mhi      = (u16*)alloc(FEAT * 2);
    u16* mlo      = (u16*)alloc(FEAT * 2);
    (void)ws_size; (void)in_sizes; (void)n_in; (void)out_size;

    const int EB = (N_EDGES + 255) / 256;       // 2344
    const int NB = (N_NODES + 255) / 256;       // 196
    const int AGG_B = (N_NODES + 7) / 8;        // 6250
    const int GEMM_B = (N_NODES + 127) / 128;   // 391
    const int WCV_B = (6 * HID * HID + 255) / 256;       // 384
    const int XSP_B = ((int)(FEAT / 4) + 255) / 256;     // 6250

    hipMemsetAsync(deg, 0, (size_t)N_NODES * 4, stream);
    detect_mode<<<1, 1024, 0, stream>>>(edges, flag);
    count_deg<<<EB, 256, 0, stream>>>(edges, flag, deg);
    scan_block<<<NB, 256, 0, stream>>>(deg, offs, blocksum);
    scan_top<<<1, 256, 0, stream>>>(blocksum, NB);
    scan_add<<<NB, 256, 0, stream>>>(offs, cursor, blocksum, NB);
    fill_csr<<<EB, 256, 0, stream>>>(edges, flag, cursor, csr);

    convert_w<<<WCV_B, 256, 0, stream>>>(Wl1, Wr1, Wl2, Wr2, Wl3, Wr3, whi, wlo);
    split_f32<<<XSP_B, 256, 0, stream>>>(x, xhi, xlo, (int)(FEAT / 4));

    // Layer 1: relu(sage(x)) -> h1 (hi/lo)
    aggregate_bf16<<<AGG_B, 256, 0, stream>>>(xhi, offs, csr, mhi, mlo);
    sage_mfma<1, 0><<<GEMM_B, 256, 0, stream>>>(mhi, mlo, xhi, xlo,
        whi, wlo, b1, h1hi, h1lo, (float*)nullptr);
    // Layer 2 -> h2 (reuses x buffers)
    aggregate_bf16<<<AGG_B, 256, 0, stream>>>(h1hi, offs, csr, mhi, mlo);
    sage_mfma<0, 0><<<GEMM_B, 256, 0, stream>>>(mhi, mlo, h1hi, h1lo,
        whi + 2 * HID * HID, wlo + 2 * HID * HID, b2, xhi, xlo, (float*)nullptr);
    // Layer 3 -> fp32 out
    aggregate_bf16<<<AGG_B, 256, 0, stream>>>(xhi, offs, csr, mhi, mlo);
    sage_mfma<0, 1><<<GEMM_B, 256, 0, stream>>>(mhi, mlo, xhi, xlo,
        whi + 4 * HID * HID, wlo + 4 * HID * HID, b3,
        (u16*)nullptr, (u16*)nullptr, out);
}

// Round 5
// 340.729 us; speedup vs baseline: 32.0958x; 1.0448x over previous
//
#include <hip/hip_runtime.h>
#include <hip/hip_bf16.h>

#define N_NODES 50000
#define N_EDGES 600000
#define HID 128

typedef __attribute__((ext_vector_type(8))) short s8v;            // 8 bf16 = 4 VGPR
typedef __attribute__((ext_vector_type(8))) unsigned short u8v;   // 8 ushort
typedef __attribute__((ext_vector_type(4))) float f4v;            // MFMA acc

// ---------------- bf16 helpers ----------------
__device__ __forceinline__ unsigned short f2bf(float x) {
    unsigned u = __float_as_uint(x);
    unsigned r = u + 0x7FFFu + ((u >> 16) & 1u);   // RNE
    return (unsigned short)(r >> 16);
}
__device__ __forceinline__ float bf2f(unsigned short u) {
    return __uint_as_float((unsigned)u << 16);
}
__device__ __forceinline__ void split_bf(float x, unsigned short& hi, unsigned short& lo) {
    hi = f2bf(x);
    lo = f2bf(x - bf2f(hi));
}

// ---------------- edge dtype detection ----------------
__global__ void detect_mode(const void* __restrict__ edges, int* __restrict__ flag) {
    __shared__ int any;
    if (threadIdx.x == 0) any = 0;
    __syncthreads();
    const int* p = (const int*)edges;
    if (p[2 * threadIdx.x + 1] != 0) any = 1;  // benign race
    __syncthreads();
    if (threadIdx.x == 0) *flag = (any == 0) ? 1 : 0;  // 1 => int64
}

__device__ __forceinline__ int edge_at(const void* edges, int mode64, long long idx) {
    return mode64 ? (int)((const long long*)edges)[idx] : ((const int*)edges)[idx];
}

// ---------------- CSR build ----------------
__global__ void count_deg(const void* __restrict__ edges, const int* __restrict__ flag,
                          int* __restrict__ deg) {
    int e = blockIdx.x * 256 + threadIdx.x;
    if (e >= N_EDGES) return;
    int m = *flag;
    int d = edge_at(edges, m, (long long)N_EDGES + e);
    if ((unsigned)d < (unsigned)N_NODES) atomicAdd(&deg[d], 1);
}

__global__ void scan_block(const int* __restrict__ deg, int* __restrict__ offs,
                           int* __restrict__ blocksum) {
    __shared__ int sm[256];
    int i = blockIdx.x * 256 + threadIdx.x;
    int v = (i < N_NODES) ? deg[i] : 0;
    sm[threadIdx.x] = v;
    __syncthreads();
    #pragma unroll
    for (int s = 1; s < 256; s <<= 1) {
        int t = (threadIdx.x >= (unsigned)s) ? sm[threadIdx.x - s] : 0;
        __syncthreads();
        sm[threadIdx.x] += t;
        __syncthreads();
    }
    if (i < N_NODES) offs[i] = sm[threadIdx.x] - v;
    if (threadIdx.x == 255) blocksum[blockIdx.x] = sm[255];
}

__global__ void scan_top(int* __restrict__ blocksum, int nblocks) {
    __shared__ int sm[256];
    int v = ((int)threadIdx.x < nblocks) ? blocksum[threadIdx.x] : 0;
    sm[threadIdx.x] = v;
    __syncthreads();
    #pragma unroll
    for (int s = 1; s < 256; s <<= 1) {
        int t = (threadIdx.x >= (unsigned)s) ? sm[threadIdx.x - s] : 0;
        __syncthreads();
        sm[threadIdx.x] += t;
        __syncthreads();
    }
    if ((int)threadIdx.x < nblocks) blocksum[threadIdx.x] = sm[threadIdx.x] - v;
    if (threadIdx.x == 255) blocksum[nblocks] = sm[255];
}

__global__ void scan_add(int* __restrict__ offs, int* __restrict__ cursor,
                         const int* __restrict__ blocksum, int nblocks) {
    int i = blockIdx.x * 256 + threadIdx.x;
    if (i < N_NODES) {
        int o = offs[i] + blocksum[blockIdx.x];
        offs[i] = o;
        cursor[i] = o;
    }
    if (i == 0) offs[N_NODES] = blocksum[nblocks];
}

__global__ void fill_csr(const void* __restrict__ edges, const int* __restrict__ flag,
                         int* __restrict__ cursor, int* __restrict__ csr) {
    int e = blockIdx.x * 256 + threadIdx.x;
    if (e >= N_EDGES) return;
    int m = *flag;
    int d = edge_at(edges, m, (long long)N_EDGES + e);
    int s = edge_at(edges, m, (long long)e);
    if ((unsigned)d >= (unsigned)N_NODES || (unsigned)s >= (unsigned)N_NODES) return;
    int pos = atomicAdd(&cursor[d], 1);
    csr[pos] = s;
}

// ---------------- precision-split conversions ----------------
__global__ void convert_w(const float* __restrict__ m0, const float* __restrict__ m1,
                          const float* __restrict__ m2, const float* __restrict__ m3,
                          const float* __restrict__ m4, const float* __restrict__ m5,
                          unsigned short* __restrict__ whi, unsigned short* __restrict__ wlo) {
    int idx = blockIdx.x * 256 + threadIdx.x;
    if (idx >= 6 * HID * HID) return;
    int mat = idx >> 14, off = idx & 16383;
    const float* src = mat == 0 ? m0 : mat == 1 ? m1 : mat == 2 ? m2
                     : mat == 3 ? m3 : mat == 4 ? m4 : m5;
    unsigned short h, l;
    split_bf(src[off], h, l);
    whi[idx] = h; wlo[idx] = l;
}

__global__ void split_f32(const float* __restrict__ x, unsigned short* __restrict__ hi,
                          unsigned short* __restrict__ lo, int n4) {
    int i = blockIdx.x * 256 + threadIdx.x;
    if (i >= n4) return;
    float4 v = ((const float4*)x)[i];
    ushort4 h, l;
    split_bf(v.x, h.x, l.x);
    split_bf(v.y, h.y, l.y);
    split_bf(v.z, h.z, l.z);
    split_bf(v.w, h.w, l.w);
    ((ushort4*)hi)[i] = h;
    ((ushort4*)lo)[i] = l;
}

// ---------------- mean aggregation (bf16-hi gather) ----------------
// 16 lanes per node, one u8v (16B) per lane covers the 256B row.
// 8-way unrolled gather -> 4 nodes/wave x 8 = 32 outstanding loads per wave
// (latency-bound kernel: MLP is the lever, not bytes).
__global__ __launch_bounds__(256) void aggregate_bf16(const unsigned short* __restrict__ h,
                                                      const int* __restrict__ offs,
                                                      const int* __restrict__ csr,
                                                      unsigned short* __restrict__ mhi,
                                                      unsigned short* __restrict__ mlo) {
    const int sub  = threadIdx.x & 15;           // lane within node group
    const int node = blockIdx.x * 16 + (threadIdx.x >> 4);
    if (node >= N_NODES) return;
    const int beg = offs[node], end = offs[node + 1];
    float a[8] = {0.f, 0.f, 0.f, 0.f, 0.f, 0.f, 0.f, 0.f};
    int p = beg;
    for (; p + 8 <= end; p += 8) {
        int s0 = csr[p],     s1 = csr[p + 1], s2 = csr[p + 2], s3 = csr[p + 3];
        int s4 = csr[p + 4], s5 = csr[p + 5], s6 = csr[p + 6], s7 = csr[p + 7];
        u8v v0 = *(const u8v*)(h + (size_t)s0 * HID + sub * 8);
        u8v v1 = *(const u8v*)(h + (size_t)s1 * HID + sub * 8);
        u8v v2 = *(const u8v*)(h + (size_t)s2 * HID + sub * 8);
        u8v v3 = *(const u8v*)(h + (size_t)s3 * HID + sub * 8);
        u8v v4 = *(const u8v*)(h + (size_t)s4 * HID + sub * 8);
        u8v v5 = *(const u8v*)(h + (size_t)s5 * HID + sub * 8);
        u8v v6 = *(const u8v*)(h + (size_t)s6 * HID + sub * 8);
        u8v v7 = *(const u8v*)(h + (size_t)s7 * HID + sub * 8);
        #pragma unroll
        for (int j = 0; j < 8; ++j)
            a[j] += ((bf2f(v0[j]) + bf2f(v1[j])) + (bf2f(v2[j]) + bf2f(v3[j])))
                  + ((bf2f(v4[j]) + bf2f(v5[j])) + (bf2f(v6[j]) + bf2f(v7[j])));
    }
    if (p + 4 <= end) {
        int s0 = csr[p], s1 = csr[p + 1], s2 = csr[p + 2], s3 = csr[p + 3];
        u8v v0 = *(const u8v*)(h + (size_t)s0 * HID + sub * 8);
        u8v v1 = *(const u8v*)(h + (size_t)s1 * HID + sub * 8);
        u8v v2 = *(const u8v*)(h + (size_t)s2 * HID + sub * 8);
        u8v v3 = *(const u8v*)(h + (size_t)s3 * HID + sub * 8);
        #pragma unroll
        for (int j = 0; j < 8; ++j)
            a[j] += (bf2f(v0[j]) + bf2f(v1[j])) + (bf2f(v2[j]) + bf2f(v3[j]));
        p += 4;
    }
    for (; p < end; ++p) {
        int s = csr[p];
        u8v v = *(const u8v*)(h + (size_t)s * HID + sub * 8);
        #pragma unroll
        for (int j = 0; j < 8; ++j) a[j] += bf2f(v[j]);
    }
    const float inv = 1.0f / fmaxf((float)(end - beg), 1.0f);
    u8v hh, ll;
    #pragma unroll
    for (int j = 0; j < 8; ++j) {
        unsigned short hj, lj;
        split_bf(a[j] * inv, hj, lj);
        hh[j] = hj; ll[j] = lj;
    }
    *(u8v*)(mhi + (size_t)node * HID + sub * 8) = hh;
    *(u8v*)(mlo + (size_t)node * HID + sub * 8) = ll;
}

// ---------------- MFMA SAGE GEMM (split-bf16, fp32-accurate) ----------------
// out[i,:] = mean[i,:] @ Wl^T + h[i,:] @ Wr^T + b  via 16x16x32 bf16 MFMA,
// 3-term split: hi*whi + lo*whi + hi*wlo (err ~2^-18).
// Block 256 thr = 4 waves; tile 128x128; wave -> 64x64 quadrant (4x4 tiles).
// B staged in LDS in 64-k panels (stride 72 shorts: banks 2-way = free, 16B
// aligned) -- loaded ONCE per block (was per-wave, 2x duplicated + 64 VGPRs).
// A register-direct, 2-deep double buffered.
template <int RELU, int FINAL>
__global__ __launch_bounds__(256) void sage_mfma(
    const unsigned short* __restrict__ Mhi, const unsigned short* __restrict__ Mlo,
    const unsigned short* __restrict__ Hhi, const unsigned short* __restrict__ Hlo,
    const unsigned short* __restrict__ Whi, const unsigned short* __restrict__ Wlo,
    const float* __restrict__ bias,
    unsigned short* __restrict__ ohi, unsigned short* __restrict__ olo,
    float* __restrict__ of32) {
    __shared__ short BhS[128 * 72];   // [col][k-in-panel], stride 72
    __shared__ short BlS[128 * 72];
    const int tid = threadIdx.x;
    const int wave = tid >> 6, lane = tid & 63;
    const int mIdx = lane & 15, q = lane >> 4;
    const int wrow = (wave & 1) * 64, wcol = (wave >> 1) * 64;
    const int rowBase = blockIdx.x * 128;

    size_t aoff[4];
    #pragma unroll
    for (int t = 0; t < 4; ++t) {
        int node = rowBase + wrow + t * 16 + mIdx;
        if (node > N_NODES - 1) node = N_NODES - 1;   // clamp; store is guarded
        aoff[t] = (size_t)node * HID + q * 8;
    }

    // B staging assignment: thread t -> col (t & 127), k-segment (t>>7)*32.
    const int bcol = tid & 127;
    const int bseg = (tid >> 7) * 32;

    f4v acc[4][4];
    #pragma unroll
    for (int a = 0; a < 4; ++a)
        #pragma unroll
        for (int b = 0; b < 4; ++b) acc[a][b] = (f4v){0.f, 0.f, 0.f, 0.f};

    s8v Ah[2][4], Al[2][4];
    auto loadA = [&](int i, int buf) {         // i = global chunk 0..7
        const unsigned short* ah_ = (i < 4) ? Mhi : Hhi;
        const unsigned short* al_ = (i < 4) ? Mlo : Hlo;
        const int kc = (i & 3) * 32;
        #pragma unroll
        for (int t = 0; t < 4; ++t) {
            Ah[buf][t] = *(const s8v*)(ah_ + aoff[t] + kc);
            Al[buf][t] = *(const s8v*)(al_ + aoff[t] + kc);
        }
    };

    loadA(0, 0);
    for (int panel = 0; panel < 4; ++panel) {  // 64-k panel
        const int ph = panel >> 1;             // 0: Wl, 1: Wr
        const int kb = (panel & 1) * 64;       // k base within phase
        const unsigned short* Wh_ = Whi + ph * HID * HID;
        const unsigned short* Wl_ = Wlo + ph * HID * HID;
        __syncthreads();                        // prev panel's LDS reads done
        {
            const unsigned short* sh = Wh_ + bcol * HID + kb + bseg;
            const unsigned short* sl = Wl_ + bcol * HID + kb + bseg;
            short* dh = BhS + bcol * 72 + bseg;
            short* dl = BlS + bcol * 72 + bseg;
            #pragma unroll
            for (int j = 0; j < 4; ++j) {
                *(s8v*)(dh + j * 8) = *(const s8v*)(sh + j * 8);
                *(s8v*)(dl + j * 8) = *(const s8v*)(sl + j * 8);
            }
        }
        __syncthreads();
        #pragma unroll
        for (int c = 0; c < 2; ++c) {          // two k=32 chunks per panel
            const int i = panel * 2 + c;
            if (i < 7) loadA(i + 1, (i + 1) & 1);
            const int kc2 = c * 32;
            s8v Bh_f[4], Bl_f[4];
            #pragma unroll
            for (int nt = 0; nt < 4; ++nt) {
                const int a = (wcol + nt * 16 + mIdx) * 72 + kc2 + q * 8;
                Bh_f[nt] = *(const s8v*)(BhS + a);
                Bl_f[nt] = *(const s8v*)(BlS + a);
            }
            const int buf = i & 1;
            #pragma unroll
            for (int mt = 0; mt < 4; ++mt)
                #pragma unroll
                for (int nt = 0; nt < 4; ++nt) {
                    acc[mt][nt] = __builtin_amdgcn_mfma_f32_16x16x32_bf16(
                        Ah[buf][mt], Bh_f[nt], acc[mt][nt], 0, 0, 0);
                    acc[mt][nt] = __builtin_amdgcn_mfma_f32_16x16x32_bf16(
                        Al[buf][mt], Bh_f[nt], acc[mt][nt], 0, 0, 0);
                    acc[mt][nt] = __builtin_amdgcn_mfma_f32_16x16x32_bf16(
                        Ah[buf][mt], Bl_f[nt], acc[mt][nt], 0, 0, 0);
                }
        }
    }

    float bv[4];
    #pragma unroll
    for (int nt = 0; nt < 4; ++nt) bv[nt] = bias[wcol + nt * 16 + mIdx];

    #pragma unroll
    for (int mt = 0; mt < 4; ++mt)
        #pragma unroll
        for (int r = 0; r < 4; ++r) {
            int node = rowBase + wrow + mt * 16 + q * 4 + r;
            if (node < N_NODES) {
                #pragma unroll
                for (int nt = 0; nt < 4; ++nt) {
                    int feat = wcol + nt * 16 + mIdx;
                    float v = acc[mt][nt][r] + bv[nt];
                    if (RELU) v = fmaxf(v, 0.f);
                    size_t oidx = (size_t)node * HID + feat;
                    if (FINAL) {
                        of32[oidx] = v;
                    } else {
                        unsigned short hh, ll;
                        split_bf(v, hh, ll);
                        ohi[oidx] = hh;
                        olo[oidx] = ll;
                    }
                }
            }
        }
}

// ---------------- launch ----------------
extern "C" void kernel_launch(void* const* d_in, const int* in_sizes, int n_in,
                              void* d_out, int out_size, void* d_ws, size_t ws_size,
                              hipStream_t stream) {
    const float* x   = (const float*)d_in[0];
    const void* edges = d_in[1];
    const float* Wl1 = (const float*)d_in[2];
    const float* Wr1 = (const float*)d_in[3];
    const float* b1  = (const float*)d_in[4];
    const float* Wl2 = (const float*)d_in[5];
    const float* Wr2 = (const float*)d_in[6];
    const float* b2  = (const float*)d_in[7];
    const float* Wl3 = (const float*)d_in[8];
    const float* Wr3 = (const float*)d_in[9];
    const float* b3  = (const float*)d_in[10];
    float* out = (float*)d_out;

    char* ws = (char*)d_ws;
    size_t off = 0;
    auto alloc = [&](size_t bytes) -> void* {
        void* p = (void*)(ws + off);
        off += (bytes + 255) & ~(size_t)255;
        return p;
    };
    typedef unsigned short u16;
    const size_t FEAT = (size_t)N_NODES * HID;
    int* flag     = (int*)alloc(256);
    int* deg      = (int*)alloc((size_t)N_NODES * 4);
    int* offs     = (int*)alloc((size_t)(N_NODES + 1) * 4);
    int* cursor   = (int*)alloc((size_t)N_NODES * 4);
    int* blocksum = (int*)alloc(256 * 4);
    int* csr      = (int*)alloc((size_t)N_EDGES * 4);
    u16* whi      = (u16*)alloc((size_t)6 * HID * HID * 2);
    u16* wlo      = (u16*)alloc((size_t)6 * HID * HID * 2);
    u16* xhi      = (u16*)alloc(FEAT * 2);   // also reused as h2_hi
    u16* xlo      = (u16*)alloc(FEAT * 2);   // also reused as h2_lo
    u16* h1hi     = (u16*)alloc(FEAT * 2);
    u16* h1lo     = (u16*)alloc(FEAT * 2);
    u16* mhi      = (u16*)alloc(FEAT * 2);
    u16* mlo      = (u16*)alloc(FEAT * 2);
    (void)ws_size; (void)in_sizes; (void)n_in; (void)out_size;

    const int EB = (N_EDGES + 255) / 256;       // 2344
    const int NB = (N_NODES + 255) / 256;       // 196
    const int AGG_B = (N_NODES + 15) / 16;      // 3125
    const int GEMM_B = (N_NODES + 127) / 128;   // 391
    const int WCV_B = (6 * HID * HID + 255) / 256;       // 384
    const int XSP_B = ((int)(FEAT / 4) + 255) / 256;     // 6250

    hipMemsetAsync(deg, 0, (size_t)N_NODES * 4, stream);
    detect_mode<<<1, 1024, 0, stream>>>(edges, flag);
    count_deg<<<EB, 256, 0, stream>>>(edges, flag, deg);
    scan_block<<<NB, 256, 0, stream>>>(deg, offs, blocksum);
    scan_top<<<1, 256, 0, stream>>>(blocksum, NB);
    scan_add<<<NB, 256, 0, stream>>>(offs, cursor, blocksum, NB);
    fill_csr<<<EB, 256, 0, stream>>>(edges, flag, cursor, csr);

    convert_w<<<WCV_B, 256, 0, stream>>>(Wl1, Wr1, Wl2, Wr2, Wl3, Wr3, whi, wlo);
    split_f32<<<XSP_B, 256, 0, stream>>>(x, xhi, xlo, (int)(FEAT / 4));

    // Layer 1: relu(sage(x)) -> h1 (hi/lo)
    aggregate_bf16<<<AGG_B, 256, 0, stream>>>(xhi, offs, csr, mhi, mlo);
    sage_mfma<1, 0><<<GEMM_B, 256, 0, stream>>>(mhi, mlo, xhi, xlo,
        whi, wlo, b1, h1hi, h1lo, (float*)nullptr);
    // Layer 2 -> h2 (reuses x buffers)
    aggregate_bf16<<<AGG_B, 256, 0, stream>>>(h1hi, offs, csr, mhi, mlo);
    sage_mfma<0, 0><<<GEMM_B, 256, 0, stream>>>(mhi, mlo, h1hi, h1lo,
        whi + 2 * HID * HID, wlo + 2 * HID * HID, b2, xhi, xlo, (float*)nullptr);
    // Layer 3 -> fp32 out
    aggregate_bf16<<<AGG_B, 256, 0, stream>>>(xhi, offs, csr, mhi, mlo);
    sage_mfma<0, 1><<<GEMM_B, 256, 0, stream>>>(mhi, mlo, xhi, xlo,
        whi + 4 * HID * HID, wlo + 4 * HID * HID, b3,
        (u16*)nullptr, (u16*)nullptr, out);
}